// Round 14
// baseline (95.622 us; speedup 1.0000x reference)
//
#include <hip/hip_runtime.h>
#include <hip/hip_bf16.h>
#include <hip/hip_fp16.h>

#define N_NODES 30000
#define N_EDGES 120000
#define IN_DIM  9
#define H       32
#define G_GRAPHS 256
#define NSTEP   66            // K = 33*32 = 1056, K-step 16

// prologue partition: zero(agg0 f16 + pooled f32) | embed | wconv | wrootT
#define ZERO_FLOATS  ((N_NODES * H) / 2 + G_GRAPHS * H)       // 488192
#define ZERO_BLOCKS  (ZERO_FLOATS / 256)                      // 1907 exact
#define EMBED_BLOCKS 3750                                     // 960000/256
#define WCONV_BLOCKS 396                                      // 3*66*512/256
#define WRT_BLOCKS   12                                       // 3*1024/256

typedef __attribute__((ext_vector_type(2)))  __fp16 half2v;
typedef __attribute__((ext_vector_type(8)))  __fp16 half8v;
typedef __attribute__((ext_vector_type(16))) float f32x16;

// --- fused prologue: zero(agg0|pooled) | node embed | wconv f16 | WrootT f16
__global__ __launch_bounds__(256) void prologue_k(
    float* __restrict__ zbase, const float* __restrict__ x,
    const float* __restrict__ Wn, const float* __restrict__ bn,
    __fp16* __restrict__ s, const float* __restrict__ Wnn,
    const float* __restrict__ bnn, __fp16* __restrict__ wf,
    const float* __restrict__ Wroot, __fp16* __restrict__ wrT)
{
    const int b = blockIdx.x;
    if (b < ZERO_BLOCKS) {
        int i = b * 256 + threadIdx.x;
        zbase[i] = 0.f;                       // agg0 (f16 pairs) + pooled
    } else if (b < ZERO_BLOCKS + EMBED_BLOCKS) {
        int gid = (b - ZERO_BLOCKS) * 256 + threadIdx.x;   // < 960000 exactly
        int n = gid >> 5, o = gid & 31;
        float acc = bn[o];
        #pragma unroll
        for (int i = 0; i < IN_DIM; ++i)
            acc = fmaf(x[n * IN_DIM + i], Wn[i * H + o], acc);
        s[gid] = (__fp16)fmaxf(acc, 0.f);                  // f16 state
    } else if (b < ZERO_BLOCKS + EMBED_BLOCKS + WCONV_BLOCKS) {
        // wf[k][step][lane][t] = f16(Wf_k[step*16 + (lane>>5)*8 + t , lane&31])
        // Wf_k = [Wnn_k (1024x32); bnn_k (32x32)]
        int gid = (b - ZERO_BLOCKS - EMBED_BLOCKS) * 256 + threadIdx.x; // < 101376
        int layer = gid / (NSTEP * 512);
        int rem   = gid % (NSTEP * 512);
        int step  = rem >> 9;
        int lane  = (rem >> 3) & 63;
        int t     = gid & 7;
        int krow  = step * 16 + ((lane >> 5) << 3) + t;    // 0..1055
        int col   = lane & 31;
        float v = (krow < 1024) ? Wnn[layer * 32768 + krow * 32 + col]
                                : bnn[layer * 1024 + (krow - 1024) * 32 + col];
        wf[gid] = (__fp16)v;
    } else {
        // wrT[k][o*32+i] = f16(Wroot[k][i*32+o])  (transposed, per-lane rows)
        int gid = (b - ZERO_BLOCKS - EMBED_BLOCKS - WCONV_BLOCKS) * 256
                  + threadIdx.x;                           // < 3072
        int layer = gid >> 10;
        int rem   = gid & 1023;
        int o = rem >> 5, i = rem & 31;
        wrT[gid] = (__fp16)Wroot[layer * 1024 + i * 32 + o];
    }
}

// ------------------------------------------------------------ edge conv MFMA
// 64-thread blocks (grid 1875, ~7.3 blocks/CU). Streaming edge order;
// packed-f16 atomics (memory-side op count is the cost driver, R12-proven).
// A-frag: row=lane&31 (edge), k=(lane>>5)*8+t
// D-frag: col=lane&31 (=o), row=(reg&3)+8*(reg>>2)+4*(lane>>5)
__global__ __launch_bounds__(64) void edge_mfma_k(
    const __fp16* __restrict__ s, const float* __restrict__ eattr,
    const int* __restrict__ ei, const float* __restrict__ We,
    const float* __restrict__ be, const __fp16* __restrict__ wf,
    __fp16* __restrict__ agg)
{
    const int lane = threadIdx.x;
    const int ebase = blockIdx.x * 64;       // 120000 % 64 == 0
    const int er = lane & 31;
    const int hi = lane >> 5;

    const int e0 = ebase + er;
    const int e1 = ebase + 32 + er;

    // prefetch dst ids (coalesced); epilogue redistributes via shfl
    const int dst_l = ei[N_EDGES + ebase + lane];

    const float a00 = eattr[e0*3+0], a01 = eattr[e0*3+1], a02 = eattr[e0*3+2];
    const float a10 = eattr[e1*3+0], a11 = eattr[e1*3+1], a12 = eattr[e1*3+2];

    const int src0 = ei[e0], src1 = ei[e1];

    // h directly as f16 chunks: lo = h[hi*8..+8), hi-chunk = h[16+hi*8..+8)
    const half8v h0lo = *(const half8v*)(s + src0 * H + hi * 8);
    const half8v h0hi = *(const half8v*)(s + src0 * H + 16 + hi * 8);
    const half8v h1lo = *(const half8v*)(s + src1 * H + hi * 8);
    const half8v h1hi = *(const half8v*)(s + src1 * H + 16 + hi * 8);

    f32x16 acc0 = {};
    f32x16 acc1 = {};
    half2v ea0 = {(__fp16)1.f, (__fp16)1.f};
    half2v ea1 = ea0;

    #pragma unroll
    for (int step = 0; step < NSTEP; ++step) {
        const int j = step >> 1;               // compile-time after unroll
        if ((step & 1) == 0 && j < 32) {
            const float w0 = We[j], w1 = We[32+j], w2 = We[64+j], bb = be[j];
            float f0 = fmaxf(fmaf(a02, w2, fmaf(a01, w1, fmaf(a00, w0, bb))), 0.f);
            float f1 = fmaxf(fmaf(a12, w2, fmaf(a11, w1, fmaf(a10, w0, bb))), 0.f);
            ea0 = __builtin_amdgcn_cvt_pkrtz(f0, f0);
            ea1 = __builtin_amdgcn_cvt_pkrtz(f1, f1);
        }
        const half8v c0 = (step & 1) ? h0hi : h0lo;
        const half8v c1 = (step & 1) ? h1hi : h1lo;
        half8v A0, A1;
        if (j < 32) {
            #pragma unroll
            for (int q = 0; q < 4; ++q) {
                half2v p0 = { c0[2*q], c0[2*q+1] };
                half2v p1 = { c1[2*q], c1[2*q+1] };
                half2v m0 = ea0 * p0;             // v_pk_mul_f16
                half2v m1 = ea1 * p1;
                A0[2*q] = m0[0]; A0[2*q+1] = m0[1];
                A1[2*q] = m1[0]; A1[2*q+1] = m1[1];
            }
        } else {                                   // bnn rows: ea == 1
            A0 = c0; A1 = c1;
        }
        const half8v B = *(const half8v*)(wf + ((step * 64 + lane) << 3));
        acc0 = __builtin_amdgcn_mfma_f32_32x32x16_f16(A0, B, acc0, 0, 0, 0);
        acc1 = __builtin_amdgcn_mfma_f32_32x32x16_f16(A1, B, acc1, 0, 0, 0);
    }

    // epilogue: pair (o, o+1) across lanes, even lanes issue pk_add_f16
    const int o = er;
    #pragma unroll
    for (int reg = 0; reg < 16; ++reg) {
        const int r = (reg & 3) + 8 * (reg >> 2) + 4 * hi;
        const int d0 = __shfl(dst_l, r);
        const int d1 = __shfl(dst_l, 32 + r);
        float v0 = acc0[reg], v1 = acc1[reg];
        float q0 = __shfl_xor(v0, 1);
        float q1 = __shfl_xor(v1, 1);
        if ((er & 1) == 0) {
            half2v p0 = __builtin_amdgcn_cvt_pkrtz(v0, q0);
            half2v p1 = __builtin_amdgcn_cvt_pkrtz(v1, q1);
            __half2 u0, u1;
            __builtin_memcpy(&u0, &p0, 4);
            __builtin_memcpy(&u1, &p1, 4);
            unsafeAtomicAdd((__half2*)(agg + d0 * H + o), u0);
            unsafeAtomicAdd((__half2*)(agg + d1 * H + o), u1);
        }
    }
}

// -- fused root(fdot2) + relu + residual; zeroes next agg; pool on last layer
__global__ __launch_bounds__(256) void finalize_k(
    const __fp16* __restrict__ agg, const __fp16* __restrict__ sin,
    const __fp16* __restrict__ wrT, const float* __restrict__ bconv,
    __fp16* __restrict__ sout, __fp16* __restrict__ aggnext,
    const int* __restrict__ batch, float* __restrict__ pooled, int do_pool)
{
    int gid = blockIdx.x * 256 + threadIdx.x;
    if (gid >= N_NODES * H) return;
    int n = gid >> 5, o = gid & 31;
    float acc = bconv[o];
    const half8v* rowv = (const half8v*)(sin + n * H);   // 4x 16B
    const half8v* wrv  = (const half8v*)(wrT + o * H);   // lane-private 64B
    #pragma unroll
    for (int q = 0; q < 4; ++q) {
        half8v r8 = rowv[q];
        half8v w8 = wrv[q];
        #pragma unroll
        for (int p = 0; p < 4; ++p) {
            half2v rp = { r8[2*p], r8[2*p+1] };
            half2v wp = { w8[2*p], w8[2*p+1] };
            acc = __builtin_amdgcn_fdot2(rp, wp, acc, false);
        }
    }
    float val = fmaxf((float)agg[gid] + acc, 0.f) + (float)sin[gid];
    if (do_pool) {
        // wave covers nodes n (lanes 0-31) and n+1 (lanes 32-63); batch is
        // sorted so they share a graph ~99% of the time -> merge atomics.
        const int lane = threadIdx.x & 63;
        const int b = batch[n];
        const float ov = __shfl_down(val, 32);
        const int   ob = __shfl_down(b, 32);
        const int   ub = __shfl_up(b, 32);
        if (lane < 32) {
            float v = (ob == b) ? val + ov : val;
            atomicAdd(pooled + b * H + o, v);
        } else if (ub != b) {
            atomicAdd(pooled + b * H + o, val);
        }
    } else {
        sout[gid] = (__fp16)val;
        aggnext[gid] = (__fp16)0.f;           // re-arm next layer's agg (free)
    }
}

// ---------------------------------------------------------------- MLP head
__global__ __launch_bounds__(128) void mlp_k(
    const float* __restrict__ pooled,
    const float* __restrict__ W1, const float* __restrict__ b1,
    const float* __restrict__ W2, const float* __restrict__ b2,
    const float* __restrict__ W3, const float* __restrict__ b3,
    float* __restrict__ out)
{
    __shared__ float p[H];
    __shared__ float h1[128];
    __shared__ float h2[64];
    const int g = blockIdx.x, t = threadIdx.x;
    if (t < H) p[t] = pooled[g * H + t];
    __syncthreads();
    float a = b1[t];
    #pragma unroll
    for (int i = 0; i < H; ++i)
        a = fmaf(p[i], W1[i * 128 + t], a);
    h1[t] = fmaxf(a, 0.f);
    __syncthreads();
    if (t < 64) {
        float a2 = b2[t];
        #pragma unroll 4
        for (int i = 0; i < 128; ++i)
            a2 = fmaf(h1[i], W2[i * 64 + t], a2);
        h2[t] = fmaxf(a2, 0.f);
    }
    __syncthreads();
    if (t < 64) {
        float v = h2[t] * W3[t];
        #pragma unroll
        for (int off = 32; off > 0; off >>= 1)
            v += __shfl_down(v, off);
        if (t == 0) out[g] = v + b3[0];
    }
}

// ---------------------------------------------------------------- launcher
extern "C" void kernel_launch(void* const* d_in, const int* in_sizes, int n_in,
                              void* d_out, int out_size, void* d_ws, size_t ws_size,
                              hipStream_t stream)
{
    const float* x     = (const float*)d_in[0];
    const int*   ei    = (const int*)  d_in[1];
    const float* eattr = (const float*)d_in[2];
    const int*   batch = (const int*)  d_in[3];
    const float* Wn    = (const float*)d_in[4];
    const float* bn    = (const float*)d_in[5];
    const float* We    = (const float*)d_in[6];
    const float* be    = (const float*)d_in[7];
    const float* Wnn   = (const float*)d_in[8];
    const float* bnn   = (const float*)d_in[9];
    const float* Wroot = (const float*)d_in[10];
    const float* bconv = (const float*)d_in[11];
    const float* W1    = (const float*)d_in[12];
    const float* b1    = (const float*)d_in[13];
    const float* W2    = (const float*)d_in[14];
    const float* b2    = (const float*)d_in[15];
    const float* W3    = (const float*)d_in[16];
    const float* b3    = (const float*)d_in[17];
    float* out = (float*)d_out;

    // ws: agg0 (f16) | pooled (f32) | agg1|agg2 (f16) | s0|s1 (f16) | wf | wrT
    __fp16* agg0  = (__fp16*)d_ws;                         // N*H f16
    float* pooled = (float*)(agg0 + N_NODES * H);          // G*H f32
    __fp16* agg1  = (__fp16*)(pooled + G_GRAPHS * H);      // N*H f16
    __fp16* agg2  = agg1 + N_NODES * H;                    // N*H f16
    __fp16* s0    = agg2 + N_NODES * H;                    // N*H f16
    __fp16* s1    = s0 + N_NODES * H;                      // N*H f16
    __fp16* wf    = s1 + N_NODES * H;                      // 3*66*512 f16
    __fp16* wrT   = wf + 3 * NSTEP * 512;                  // 3*1024 f16
    __fp16* aggs[4] = {agg0, agg1, agg2, agg0};

    const int nw_grid = (N_NODES * H + 255) / 256;   // 3750
    const int e_grid  = N_EDGES / 64;                // 1875

    prologue_k<<<ZERO_BLOCKS + EMBED_BLOCKS + WCONV_BLOCKS + WRT_BLOCKS,
                 256, 0, stream>>>(
        (float*)d_ws, x, Wn, bn, s0, Wnn, bnn, wf, Wroot, wrT);

    const __fp16* sin = s0;
    __fp16* sout = s1;
    for (int k = 0; k < 3; ++k) {
        edge_mfma_k<<<e_grid, 64, 0, stream>>>(sin, eattr, ei, We, be,
                                               wf + k * NSTEP * 512, aggs[k]);
        finalize_k<<<nw_grid, 256, 0, stream>>>(aggs[k], sin,
                                                wrT + k * 1024,
                                                bconv + k * H, sout,
                                                aggs[k + 1],
                                                batch, pooled, (k == 2) ? 1 : 0);
        const __fp16* tmp = sout; sout = (__fp16*)sin; sin = tmp;
    }

    mlp_k<<<G_GRAPHS, 128, 0, stream>>>(pooled, W1, b1, W2, b2, W3, b3, out);
}

// Round 15
// 95.053 us; speedup vs baseline: 1.0060x; 1.0060x over previous
//
#include <hip/hip_runtime.h>
#include <hip/hip_bf16.h>
#include <hip/hip_fp16.h>

#define N_NODES 30000
#define N_EDGES 120000
#define IN_DIM  9
#define H       32
#define G_GRAPHS 256
#define NSTEP   66            // K = 33*32 = 1056, K-step 16

// prologue partition: zero(agg0 f16 + pooled f32) | embed | wconv | wrootT
#define ZERO_FLOATS  ((N_NODES * H) / 2 + G_GRAPHS * H)       // 488192
#define ZERO_BLOCKS  (ZERO_FLOATS / 256)                      // 1907 exact
#define EMBED_BLOCKS 3750                                     // 960000/256
#define WCONV_BLOCKS 396                                      // 3*66*512/256
#define WRT_BLOCKS   12                                       // 3*1024/256

typedef __attribute__((ext_vector_type(2)))  __fp16 half2v;
typedef __attribute__((ext_vector_type(8)))  __fp16 half8v;
typedef __attribute__((ext_vector_type(16))) float f32x16;

// --- fused prologue: zero(agg0|pooled) | node embed | wconv f16 | WrootT f16
__global__ __launch_bounds__(256) void prologue_k(
    float* __restrict__ zbase, const float* __restrict__ x,
    const float* __restrict__ Wn, const float* __restrict__ bn,
    __fp16* __restrict__ s, const float* __restrict__ Wnn,
    const float* __restrict__ bnn, __fp16* __restrict__ wf,
    const float* __restrict__ Wroot, __fp16* __restrict__ wrT)
{
    const int b = blockIdx.x;
    if (b < ZERO_BLOCKS) {
        int i = b * 256 + threadIdx.x;
        zbase[i] = 0.f;                       // agg0 (f16 pairs) + pooled
    } else if (b < ZERO_BLOCKS + EMBED_BLOCKS) {
        int gid = (b - ZERO_BLOCKS) * 256 + threadIdx.x;   // < 960000 exactly
        int n = gid >> 5, o = gid & 31;
        float acc = bn[o];
        #pragma unroll
        for (int i = 0; i < IN_DIM; ++i)
            acc = fmaf(x[n * IN_DIM + i], Wn[i * H + o], acc);
        s[gid] = (__fp16)fmaxf(acc, 0.f);                  // f16 state
    } else if (b < ZERO_BLOCKS + EMBED_BLOCKS + WCONV_BLOCKS) {
        // wf[k][step][lane][t] = f16(Wf_k[step*16 + (lane>>5)*8 + t , lane&31])
        // Wf_k = [Wnn_k (1024x32); bnn_k (32x32)]
        int gid = (b - ZERO_BLOCKS - EMBED_BLOCKS) * 256 + threadIdx.x; // < 101376
        int layer = gid / (NSTEP * 512);
        int rem   = gid % (NSTEP * 512);
        int step  = rem >> 9;
        int lane  = (rem >> 3) & 63;
        int t     = gid & 7;
        int krow  = step * 16 + ((lane >> 5) << 3) + t;    // 0..1055
        int col   = lane & 31;
        float v = (krow < 1024) ? Wnn[layer * 32768 + krow * 32 + col]
                                : bnn[layer * 1024 + (krow - 1024) * 32 + col];
        wf[gid] = (__fp16)v;
    } else {
        // wrT[k][o*32+i] = f16(Wroot[k][i*32+o])  (transposed, per-lane rows)
        int gid = (b - ZERO_BLOCKS - EMBED_BLOCKS - WCONV_BLOCKS) * 256
                  + threadIdx.x;                           // < 3072
        int layer = gid >> 10;
        int rem   = gid & 1023;
        int o = rem >> 5, i = rem & 31;
        wrT[gid] = (__fp16)Wroot[layer * 1024 + i * 32 + o];
    }
}

// ------------------------------------------------------------ edge conv MFMA
// 64-thread blocks (grid 1875, ~7.3 blocks/CU). Streaming edge order;
// packed-f16 atomics (memory-side op count is the cost driver, R12-proven).
// A-frag: row=lane&31 (edge), k=(lane>>5)*8+t
// D-frag: col=lane&31 (=o), row=(reg&3)+8*(reg>>2)+4*(lane>>5)
__global__ __launch_bounds__(64) void edge_mfma_k(
    const __fp16* __restrict__ s, const float* __restrict__ eattr,
    const int* __restrict__ ei, const float* __restrict__ We,
    const float* __restrict__ be, const __fp16* __restrict__ wf,
    __fp16* __restrict__ agg)
{
    const int lane = threadIdx.x;
    const int ebase = blockIdx.x * 64;       // 120000 % 64 == 0
    const int er = lane & 31;
    const int hi = lane >> 5;

    const int e0 = ebase + er;
    const int e1 = ebase + 32 + er;

    // prefetch dst ids (coalesced); epilogue redistributes via shfl
    const int dst_l = ei[N_EDGES + ebase + lane];

    const float a00 = eattr[e0*3+0], a01 = eattr[e0*3+1], a02 = eattr[e0*3+2];
    const float a10 = eattr[e1*3+0], a11 = eattr[e1*3+1], a12 = eattr[e1*3+2];

    const int src0 = ei[e0], src1 = ei[e1];

    // h directly as f16 chunks: lo = h[hi*8..+8), hi-chunk = h[16+hi*8..+8)
    const half8v h0lo = *(const half8v*)(s + src0 * H + hi * 8);
    const half8v h0hi = *(const half8v*)(s + src0 * H + 16 + hi * 8);
    const half8v h1lo = *(const half8v*)(s + src1 * H + hi * 8);
    const half8v h1hi = *(const half8v*)(s + src1 * H + 16 + hi * 8);

    f32x16 acc0 = {};
    f32x16 acc1 = {};
    half2v ea0 = {(__fp16)1.f, (__fp16)1.f};
    half2v ea1 = ea0;

    #pragma unroll
    for (int step = 0; step < NSTEP; ++step) {
        const int j = step >> 1;               // compile-time after unroll
        if ((step & 1) == 0 && j < 32) {
            const float w0 = We[j], w1 = We[32+j], w2 = We[64+j], bb = be[j];
            float f0 = fmaxf(fmaf(a02, w2, fmaf(a01, w1, fmaf(a00, w0, bb))), 0.f);
            float f1 = fmaxf(fmaf(a12, w2, fmaf(a11, w1, fmaf(a10, w0, bb))), 0.f);
            ea0 = __builtin_amdgcn_cvt_pkrtz(f0, f0);
            ea1 = __builtin_amdgcn_cvt_pkrtz(f1, f1);
        }
        const half8v c0 = (step & 1) ? h0hi : h0lo;
        const half8v c1 = (step & 1) ? h1hi : h1lo;
        half8v A0, A1;
        if (j < 32) {
            #pragma unroll
            for (int q = 0; q < 4; ++q) {
                half2v p0 = { c0[2*q], c0[2*q+1] };
                half2v p1 = { c1[2*q], c1[2*q+1] };
                half2v m0 = ea0 * p0;             // v_pk_mul_f16
                half2v m1 = ea1 * p1;
                A0[2*q] = m0[0]; A0[2*q+1] = m0[1];
                A1[2*q] = m1[0]; A1[2*q+1] = m1[1];
            }
        } else {                                   // bnn rows: ea == 1
            A0 = c0; A1 = c1;
        }
        const half8v B = *(const half8v*)(wf + ((step * 64 + lane) << 3));
        acc0 = __builtin_amdgcn_mfma_f32_32x32x16_f16(A0, B, acc0, 0, 0, 0);
        acc1 = __builtin_amdgcn_mfma_f32_32x32x16_f16(A1, B, acc1, 0, 0, 0);
    }

    // epilogue: pair (o, o+1) across lanes, even lanes issue pk_add_f16
    const int o = er;
    #pragma unroll
    for (int reg = 0; reg < 16; ++reg) {
        const int r = (reg & 3) + 8 * (reg >> 2) + 4 * hi;
        const int d0 = __shfl(dst_l, r);
        const int d1 = __shfl(dst_l, 32 + r);
        float v0 = acc0[reg], v1 = acc1[reg];
        float q0 = __shfl_xor(v0, 1);
        float q1 = __shfl_xor(v1, 1);
        if ((er & 1) == 0) {
            half2v p0 = __builtin_amdgcn_cvt_pkrtz(v0, q0);
            half2v p1 = __builtin_amdgcn_cvt_pkrtz(v1, q1);
            __half2 u0, u1;
            __builtin_memcpy(&u0, &p0, 4);
            __builtin_memcpy(&u1, &p1, 4);
            unsafeAtomicAdd((__half2*)(agg + d0 * H + o), u0);
            unsafeAtomicAdd((__half2*)(agg + d1 * H + o), u1);
        }
    }
}

// -- fused root(fdot2) + relu + residual; zeroes next agg; pool on last layer
__global__ __launch_bounds__(256) void finalize_k(
    const __fp16* __restrict__ agg, const __fp16* __restrict__ sin,
    const __fp16* __restrict__ wrT, const float* __restrict__ bconv,
    __fp16* __restrict__ sout, __fp16* __restrict__ aggnext,
    const int* __restrict__ batch, float* __restrict__ pooled, int do_pool)
{
    int gid = blockIdx.x * 256 + threadIdx.x;
    if (gid >= N_NODES * H) return;
    int n = gid >> 5, o = gid & 31;
    float acc = bconv[o];
    const half8v* rowv = (const half8v*)(sin + n * H);   // 4x 16B
    const half8v* wrv  = (const half8v*)(wrT + o * H);   // lane-private 64B
    #pragma unroll
    for (int q = 0; q < 4; ++q) {
        half8v r8 = rowv[q];
        half8v w8 = wrv[q];
        #pragma unroll
        for (int p = 0; p < 4; ++p) {
            half2v rp = { r8[2*p], r8[2*p+1] };
            half2v wp = { w8[2*p], w8[2*p+1] };
            acc = __builtin_amdgcn_fdot2(rp, wp, acc, false);
        }
    }
    float val = fmaxf((float)agg[gid] + acc, 0.f) + (float)sin[gid];
    if (do_pool) {
        // wave covers nodes n (lanes 0-31) and n+1 (lanes 32-63); batch is
        // sorted so they share a graph ~99% of the time -> merge atomics.
        const int lane = threadIdx.x & 63;
        const int b = batch[n];
        const float ov = __shfl_down(val, 32);
        const int   ob = __shfl_down(b, 32);
        const int   ub = __shfl_up(b, 32);
        if (lane < 32) {
            float v = (ob == b) ? val + ov : val;
            atomicAdd(pooled + b * H + o, v);
        } else if (ub != b) {
            atomicAdd(pooled + b * H + o, val);
        }
    } else {
        sout[gid] = (__fp16)val;
        aggnext[gid] = (__fp16)0.f;           // re-arm next layer's agg (free)
    }
}

// ---------------------------------------------------------------- MLP head
__global__ __launch_bounds__(128) void mlp_k(
    const float* __restrict__ pooled,
    const float* __restrict__ W1, const float* __restrict__ b1,
    const float* __restrict__ W2, const float* __restrict__ b2,
    const float* __restrict__ W3, const float* __restrict__ b3,
    float* __restrict__ out)
{
    __shared__ float p[H];
    __shared__ float h1[128];
    __shared__ float h2[64];
    const int g = blockIdx.x, t = threadIdx.x;
    if (t < H) p[t] = pooled[g * H + t];
    __syncthreads();
    float a = b1[t];
    #pragma unroll
    for (int i = 0; i < H; ++i)
        a = fmaf(p[i], W1[i * 128 + t], a);
    h1[t] = fmaxf(a, 0.f);
    __syncthreads();
    if (t < 64) {
        float a2 = b2[t];
        #pragma unroll 4
        for (int i = 0; i < 128; ++i)
            a2 = fmaf(h1[i], W2[i * 64 + t], a2);
        h2[t] = fmaxf(a2, 0.f);
    }
    __syncthreads();
    if (t < 64) {
        float v = h2[t] * W3[t];
        #pragma unroll
        for (int off = 32; off > 0; off >>= 1)
            v += __shfl_down(v, off);
        if (t == 0) out[g] = v + b3[0];
    }
}

// ---------------------------------------------------------------- launcher
extern "C" void kernel_launch(void* const* d_in, const int* in_sizes, int n_in,
                              void* d_out, int out_size, void* d_ws, size_t ws_size,
                              hipStream_t stream)
{
    const float* x     = (const float*)d_in[0];
    const int*   ei    = (const int*)  d_in[1];
    const float* eattr = (const float*)d_in[2];
    const int*   batch = (const int*)  d_in[3];
    const float* Wn    = (const float*)d_in[4];
    const float* bn    = (const float*)d_in[5];
    const float* We    = (const float*)d_in[6];
    const float* be    = (const float*)d_in[7];
    const float* Wnn   = (const float*)d_in[8];
    const float* bnn   = (const float*)d_in[9];
    const float* Wroot = (const float*)d_in[10];
    const float* bconv = (const float*)d_in[11];
    const float* W1    = (const float*)d_in[12];
    const float* b1    = (const float*)d_in[13];
    const float* W2    = (const float*)d_in[14];
    const float* b2    = (const float*)d_in[15];
    const float* W3    = (const float*)d_in[16];
    const float* b3    = (const float*)d_in[17];
    float* out = (float*)d_out;

    // ws: agg0 (f16) | pooled (f32) | agg1|agg2 (f16) | s0|s1 (f16) | wf | wrT
    __fp16* agg0  = (__fp16*)d_ws;                         // N*H f16
    float* pooled = (float*)(agg0 + N_NODES * H);          // G*H f32
    __fp16* agg1  = (__fp16*)(pooled + G_GRAPHS * H);      // N*H f16
    __fp16* agg2  = agg1 + N_NODES * H;                    // N*H f16
    __fp16* s0    = agg2 + N_NODES * H;                    // N*H f16
    __fp16* s1    = s0 + N_NODES * H;                      // N*H f16
    __fp16* wf    = s1 + N_NODES * H;                      // 3*66*512 f16
    __fp16* wrT   = wf + 3 * NSTEP * 512;                  // 3*1024 f16
    __fp16* aggs[4] = {agg0, agg1, agg2, agg0};

    const int nw_grid = (N_NODES * H + 255) / 256;   // 3750
    const int e_grid  = N_EDGES / 64;                // 1875

    prologue_k<<<ZERO_BLOCKS + EMBED_BLOCKS + WCONV_BLOCKS + WRT_BLOCKS,
                 256, 0, stream>>>(
        (float*)d_ws, x, Wn, bn, s0, Wnn, bnn, wf, Wroot, wrT);

    const __fp16* sin = s0;
    __fp16* sout = s1;
    for (int k = 0; k < 3; ++k) {
        edge_mfma_k<<<e_grid, 64, 0, stream>>>(sin, eattr, ei, We, be,
                                               wf + k * NSTEP * 512, aggs[k]);
        finalize_k<<<nw_grid, 256, 0, stream>>>(aggs[k], sin,
                                                wrT + k * 1024,
                                                bconv + k * H, sout,
                                                aggs[k + 1],
                                                batch, pooled, (k == 2) ? 1 : 0);
        const __fp16* tmp = sout; sout = (__fp16*)sin; sin = tmp;
    }

    mlp_k<<<G_GRAPHS, 128, 0, stream>>>(pooled, W1, b1, W2, b2, W3, b3, out);
}